// Round 8
// baseline (889.512 us; speedup 1.0000x reference)
//
#include <hip/hip_runtime.h>
#include <hip/hip_bf16.h>

using u16 = unsigned short;
using u32 = unsigned int;

typedef __bf16 v8bf __attribute__((ext_vector_type(8)));
typedef float  v4f  __attribute__((ext_vector_type(4)));

#define ST   68    // u16 stride, stage [edge][ch] layout (8B-aligned rows; b128@8B OK - proven r5/r6)
#define ST2  136   // u16 stride, stage [ch][edge] transposed layout (16B-aligned rows)
#define STK  132   // u16 stride for 128-wide node-GEMM LDS rows
#define EPB  128   // edges per block in agg_k
#define CAP  2048  // max bucket size for in-LDS reorder
#define OVFCAP 65536

__device__ __forceinline__ u16 f2b(float f){
  u32 u = __builtin_bit_cast(u32, f);
  u += 0x7FFFu + ((u >> 16) & 1u);
  return (u16)(u >> 16);
}
__device__ __forceinline__ float b2f(u16 b){
  u32 u = ((u32)b) << 16;
  return __builtin_bit_cast(float, u);
}
__device__ __forceinline__ u32 pkbf(float lo, float hi){   // hw packed cvt, RNE
  union { __hip_bfloat162 h; u32 u; } cv;
  cv.h = __float22bfloat162_rn(make_float2(lo, hi));
  return cv.u;
}

union bfu { v8bf v; u16 s[8]; u32 w[4]; };

__device__ __forceinline__ v8bf zero8(){
  bfu u;
  #pragma unroll
  for (int i = 0; i < 4; i++) u.w[i] = 0;
  return u.v;
}

// ---------------- weight image prep (once) ----------------

__global__ __launch_bounds__(256) void prep_k(const float* __restrict__ W1, const float* __restrict__ W2,
                                              u16* __restrict__ wimg1, u16* __restrict__ wimg2){
  int tid = threadIdx.x;
  for (int i = tid; i < 2048; i += 256){ int r = i >> 5, k = i & 31; wimg1[i] = (k < 8) ? f2b(W1[r*8+k]) : (u16)0; }
  for (int i = tid; i < 64*ST; i += 256){ int n = i / ST, k = i % ST; wimg2[i] = (k < 64) ? f2b(W2[n*64+k]) : (u16)0; }
}

// ---------------- counting sort by target, bucketed 2-phase ----------------

__global__ __launch_bounds__(256) void hist_k(const int* __restrict__ col, int* __restrict__ counts, int E){
  int e = blockIdx.x*256 + threadIdx.x;
  if (e < E) atomicAdd(&counts[col[e]], 1);
}

__global__ __launch_bounds__(1024) void scan1_k(const int* __restrict__ counts, int* __restrict__ start,
                                                int* __restrict__ bsum, int N){
  __shared__ int s[1024];
  int tid = threadIdx.x;
  int i = blockIdx.x*1024 + tid;
  int v = (i < N) ? counts[i] : 0;
  s[tid] = v; __syncthreads();
  for (int off = 1; off < 1024; off <<= 1){
    int t = (tid >= off) ? s[tid-off] : 0;
    __syncthreads();
    s[tid] += t;
    __syncthreads();
  }
  if (i < N) start[i] = s[tid] - v;
  if (tid == 1023) bsum[blockIdx.x] = s[1023];
}

__global__ __launch_bounds__(1024) void scan2_k(int* __restrict__ bsum, int nb, int* __restrict__ start,
                                                int N, int E){
  __shared__ int s[1024];
  int tid = threadIdx.x;
  int v = (tid < nb) ? bsum[tid] : 0;
  s[tid] = v; __syncthreads();
  for (int off = 1; off < 1024; off <<= 1){
    int t = (tid >= off) ? s[tid-off] : 0;
    __syncthreads();
    s[tid] += t;
    __syncthreads();
  }
  if (tid < nb) bsum[tid] = s[tid] - v;
  if (tid == 0) start[N] = E;
}

__global__ __launch_bounds__(1024) void scan3_k(int* __restrict__ start, const int* __restrict__ bsum,
                                                int* __restrict__ bcur, int N){
  int i = blockIdx.x*1024 + threadIdx.x;
  if (i < N){
    int v = start[i] + bsum[blockIdx.x];
    start[i] = v;
    if ((i & 31) == 0) bcur[i >> 5] = v;   // bucket head cursor
  }
}

// phase 1: scatter 24B record {ea bf16x8, src, tgt} into its BUCKET region (order within bucket arbitrary)
__global__ __launch_bounds__(256) void scat1_k(const int* __restrict__ row, const int* __restrict__ col,
                                               const float* __restrict__ ea, int* __restrict__ bcur,
                                               u32* __restrict__ rec, int E){
  int e = blockIdx.x*256 + threadIdx.x;
  if (e < E){
    int c = col[e];
    int s = row[e];
    const float4* eap = (const float4*)(ea + (size_t)e*8);
    float4 a0 = eap[0], a1 = eap[1];
    u32 w0 = pkbf(a0.x, a0.y), w1 = pkbf(a0.z, a0.w);
    u32 w2 = pkbf(a1.x, a1.y), w3 = pkbf(a1.z, a1.w);
    int p = atomicAdd(&bcur[c >> 5], 1);
    int2* r2 = (int2*)(rec + (size_t)p*6);
    r2[0] = make_int2((int)w0, (int)w1);
    r2[1] = make_int2((int)w2, (int)w3);
    r2[2] = make_int2(s, c);
  }
}

// phase 2: one block per bucket; in-LDS counting re-sort of the bucket's contiguous region
__global__ __launch_bounds__(256) void scat2_k(const int* __restrict__ start, u32* __restrict__ rec,
                                               u32* __restrict__ ovf, int* __restrict__ ovf_cnt, int N){
  __shared__ u32 buf[CAP*6];
  __shared__ int cnt[32];
  __shared__ int s_off;
  int b = blockIdx.x;
  int t0 = b*32;
  int tmax = N - t0; if (tmax > 32) tmax = 32;
  int lo = start[t0];
  int hi = start[t0 + tmax];
  int sz = hi - lo;
  if (sz <= 0) return;
  int tid = threadIdx.x;
  if (tid < tmax) cnt[tid] = start[t0 + tid];
  if (sz <= CAP){
    for (int i = tid; i < sz*6; i += 256) buf[i] = rec[(size_t)lo*6 + i];
    __syncthreads();
    for (int r = tid; r < sz; r += 256){
      const u32* sp = &buf[r*6];
      int tgt = (int)sp[5];
      int pos = atomicAdd(&cnt[tgt - t0], 1);
      int2* d = (int2*)(rec + (size_t)pos*6);
      d[0] = make_int2((int)sp[0], (int)sp[1]);
      d[1] = make_int2((int)sp[2], (int)sp[3]);
      d[2] = make_int2((int)sp[4], (int)sp[5]);
    }
  } else {                                   // statistically impossible fallback (Poisson(512) > 2048)
    if (tid == 0) s_off = atomicAdd(ovf_cnt, sz);
    __syncthreads();
    int off = s_off;
    if (off + sz > OVFCAP) return;           // give up (never)
    for (int i = tid; i < sz*6; i += 256) ovf[(size_t)off*6 + i] = rec[(size_t)lo*6 + i];
    __threadfence();
    __syncthreads();
    volatile u32* ov = ovf + (size_t)off*6;
    for (int r = tid; r < sz; r += 256){
      u32 s0 = ov[r*6], s1 = ov[r*6+1], s2 = ov[r*6+2], s3 = ov[r*6+3], s4 = ov[r*6+4], s5 = ov[r*6+5];
      int pos = atomicAdd(&cnt[(int)s5 - t0], 1);
      u32* d = rec + (size_t)pos*6;
      d[0]=s0; d[1]=s1; d[2]=s2; d[3]=s3; d[4]=s4; d[5]=s5;
    }
  }
}

// ---------------- fused edge-MLP (both layers MFMA, packed LDS) + segmented aggregation ----------------

template<int MODE>   // 0: degree (xv=1)   1: layer (gather V bf16)
__global__ __launch_bounds__(256) void agg_k(const u32* __restrict__ rec, const u32* __restrict__ wimg1,
                                             const u32* __restrict__ wimg2,
                                             const u16* __restrict__ V, float* __restrict__ U, int E){
  __shared__ __align__(16) u16 stage[128*ST];   // phase A: [edge][ST]: ea then t1 ; phase B (aliased): [ch][ST2] ew
  __shared__ __align__(16) u16 w2s[64*ST];
  __shared__ __align__(16) u16 w1s[64*32];
  __shared__ int sl[EPB], tl[EPB];
  int tid = threadIdx.x;
  int j0 = blockIdx.x*EPB;

  if (tid < EPB){
    int j = j0 + tid;
    int2 a = make_int2(0,0), b = make_int2(0,0), c = make_int2(0,0);
    if (j < E){
      const int2* r2 = (const int2*)(rec + (size_t)j*6);
      a = r2[0]; b = r2[1]; c = r2[2];
    }
    sl[tid] = c.x;
    tl[tid] = c.y;
    *(int2*)&stage[tid*ST]     = a;
    *(int2*)&stage[tid*ST + 4] = b;
  }
  for (int i = tid; i < 1024; i += 256) ((u32*)w1s)[i] = wimg1[i];
  for (int i = tid; i < 2176; i += 256) ((u32*)w2s)[i] = wimg2[i];
  __syncthreads();

  int w = tid >> 6, lane = tid & 63;
  int m16 = lane & 15, quad = lane >> 4;
  int base = w*32;

  // ---- layer 1: D[h][edge] = W1(padded) x ea^T.  A = W1 [h][k32], B = ea^T (quads 1-3 zero) ----
  v8bf be[2];
  #pragma unroll
  for (int ni = 0; ni < 2; ni++){
    be[ni] = zero8();
    if (quad == 0) be[ni] = *(const v8bf*)&stage[(base + ni*16 + m16)*ST];   // 8B-aligned b128 (OK on gfx950)
  }
  v4f acc1[4][2];
  #pragma unroll
  for (int mi = 0; mi < 4; mi++)
    #pragma unroll
    for (int ni = 0; ni < 2; ni++) acc1[mi][ni] = (v4f){0.f,0.f,0.f,0.f};
  #pragma unroll
  for (int mi = 0; mi < 4; mi++){
    v8bf aw = *(const v8bf*)&w1s[(mi*16 + m16)*32 + quad*8];
    #pragma unroll
    for (int ni = 0; ni < 2; ni++)
      acc1[mi][ni] = __builtin_amdgcn_mfma_f32_16x16x32_bf16(aw, be[ni], acc1[mi][ni], 0, 0, 0);
  }
  // t1 -> stage[edge][h], rows = edge = base+ni*16+m16, cols h = mi*16+quad*4+r  (packed b64)
  #pragma unroll
  for (int ni = 0; ni < 2; ni++)
    #pragma unroll
    for (int mi = 0; mi < 4; mi++){
      u32 p0 = pkbf(fmaxf(acc1[mi][ni][0],0.f), fmaxf(acc1[mi][ni][1],0.f));
      u32 p1 = pkbf(fmaxf(acc1[mi][ni][2],0.f), fmaxf(acc1[mi][ni][3],0.f));
      *(uint2*)&stage[(base + ni*16 + m16)*ST + mi*16 + quad*4] = make_uint2(p0, p1);
    }

  // ---- layer 2: ew = relu(t1 @ W2^T); A = t1 [edge][k], B = W2 [o][k] (wave-local reads) ----
  v4f acc2[2][4];
  #pragma unroll
  for (int mi = 0; mi < 2; mi++)
    #pragma unroll
    for (int ni = 0; ni < 4; ni++) acc2[mi][ni] = (v4f){0.f,0.f,0.f,0.f};
  #pragma unroll
  for (int ks = 0; ks < 2; ks++){
    v8bf bf[4];
    #pragma unroll
    for (int ni = 0; ni < 4; ni++)
      bf[ni] = *(const v8bf*)&w2s[(ni*16 + m16)*ST + ks*32 + quad*8];
    #pragma unroll
    for (int mi = 0; mi < 2; mi++){
      v8bf af = *(const v8bf*)&stage[(base + mi*16 + m16)*ST + ks*32 + quad*8];
      #pragma unroll
      for (int ni = 0; ni < 4; ni++)
        acc2[mi][ni] = __builtin_amdgcn_mfma_f32_16x16x32_bf16(af, bf[ni], acc2[mi][ni], 0, 0, 0);
    }
  }
  __syncthreads();   // all reads of stage done before aliased transposed writes

  // ew -> stage_t[ch][edge] (aliased), rows ch = ni*16+m16, cols edge = base+mi*16+quad*4+r (packed b64)
  #pragma unroll
  for (int mi = 0; mi < 2; mi++)
    #pragma unroll
    for (int ni = 0; ni < 4; ni++){
      u32 p0 = pkbf(fmaxf(acc2[mi][ni][0],0.f), fmaxf(acc2[mi][ni][1],0.f));
      u32 p1 = pkbf(fmaxf(acc2[mi][ni][2],0.f), fmaxf(acc2[mi][ni][3],0.f));
      *(uint2*)&stage[(ni*16 + m16)*ST2 + base + mi*16 + quad*4] = make_uint2(p0, p1);
    }

  // ---- segmented scan over this wave's 32 sorted edges; lane = channel; b128 ew reads ----
  int lim = E - (j0 + base); if (lim > 32) lim = 32;
  if (lim == 32){
    float s = 0.f;
    int cur = tl[base];
    #pragma unroll
    for (int q0 = 0; q0 < 32; q0 += 8){
      uint4 pk = *(const uint4*)&stage[lane*ST2 + base + q0];
      u32 pw[4] = {pk.x, pk.y, pk.z, pk.w};
      float xv[8];
      #pragma unroll
      for (int q = 0; q < 8; q++)
        xv[q] = MODE ? b2f(V[(size_t)sl[base+q0+q]*64 + lane]) : 1.f;
      #pragma unroll
      for (int q = 0; q < 8; q++){
        u32 wb = (q & 1) ? (pw[q>>1] & 0xffff0000u) : (pw[q>>1] << 16);
        float wv = __builtin_bit_cast(float, wb);
        int t = tl[base+q0+q];
        if (t != cur){ atomicAdd(&U[(size_t)cur*64 + lane], s); s = 0.f; cur = t; }
        s = fmaf(wv, xv[q], s);
      }
    }
    atomicAdd(&U[(size_t)cur*64 + lane], s);
  } else if (lim > 0){
    float s = 0.f;
    int cur = tl[base];
    for (int q = 0; q < lim; q++){
      float wv = b2f(stage[lane*ST2 + base + q]);
      float xv = MODE ? b2f(V[(size_t)sl[base+q]*64 + lane]) : 1.f;
      int t = tl[base+q];
      if (t != cur){ atomicAdd(&U[(size_t)cur*64 + lane], s); s = 0.f; cur = t; }
      s += wv*xv;
    }
    atomicAdd(&U[(size_t)cur*64 + lane], s);
  }
}

__global__ __launch_bounds__(256) void degfin_k(float* __restrict__ U, float* __restrict__ dinv, int NH){
  int i = blockIdx.x*256 + threadIdx.x;
  if (i < NH){
    dinv[i] = rsqrtf(1.f + U[i]);
    U[i] = 0.f;
  }
}

// ---------------- xlin via MFMA: 64 nodes/block; xlin stored bf16 ----------------

__global__ __launch_bounds__(256) void xlin_k(const float* __restrict__ x, const float* __restrict__ Wi,
                                              const float* __restrict__ bi, const float* __restrict__ wconv0,
                                              const float* __restrict__ dinv,
                                              u16* __restrict__ xlin, u16* __restrict__ V, int N){
  __shared__ __align__(16) u16 wb[64*STK];
  __shared__ __align__(16) u16 as[64*STK];
  int tid = threadIdx.x;
  for (int i = tid; i < 8192; i += 256){ int o = i >> 7, k = i & 127; wb[o*STK+k] = f2b(Wi[i]); }
  int nb0 = blockIdx.x*64;
  for (int i = tid; i < 8192; i += 256){
    int nn = i >> 7, k = i & 127; int n = nb0 + nn;
    as[nn*STK+k] = (n < N) ? f2b(x[(size_t)n*128 + k]) : (u16)0;
  }
  __syncthreads();
  int w = tid >> 6, lane = tid & 63;
  int m16 = lane & 15, quad = lane >> 4;
  int wbase = w*16;
  v8bf af[4];
  #pragma unroll
  for (int ks = 0; ks < 4; ks++) af[ks] = *(const v8bf*)&as[(wbase+m16)*STK + ks*32 + quad*8];
  v4f acc[4];
  #pragma unroll
  for (int ni = 0; ni < 4; ni++) acc[ni] = (v4f){0.f,0.f,0.f,0.f};
  #pragma unroll
  for (int ks = 0; ks < 4; ks++){
    #pragma unroll
    for (int ni = 0; ni < 4; ni++){
      v8bf bf = *(const v8bf*)&wb[(ni*16+m16)*STK + ks*32 + quad*8];
      acc[ni] = __builtin_amdgcn_mfma_f32_16x16x32_bf16(af[ks], bf, acc[ni], 0, 0, 0);
    }
  }
  #pragma unroll
  for (int ni = 0; ni < 4; ni++){
    int c = ni*16 + m16;
    float wc = wconv0[c], bc = bi[c];
    #pragma unroll
    for (int r = 0; r < 4; r++){
      int n = nb0 + wbase + quad*4 + r;
      if (n < N){
        float val = acc[ni][r] + bc;
        size_t idx = (size_t)n*64 + c;
        xlin[idx] = f2b(val);
        V[idx] = f2b(fmaxf(val, 0.f) * wc * dinv[idx]);
      }
    }
  }
}

// ---------------- epilogue via MFMA: residual folded as identity in Wl ----------------

__global__ __launch_bounds__(256) void epi_k(const u16* __restrict__ xlin, const float* __restrict__ dinv,
                                             float* __restrict__ U, u16* __restrict__ V,
                                             const float* __restrict__ Wl, const float* __restrict__ bconv,
                                             const float* __restrict__ wconv_next, const float* __restrict__ Wo,
                                             float* __restrict__ out, int N, int last){
  __shared__ __align__(16) u16 wb[64*STK];
  __shared__ __align__(16) u16 an[64*STK];
  int tid = threadIdx.x;
  for (int i = tid; i < 8192; i += 256){
    int o = i >> 7, c = i & 127;
    wb[o*STK+c] = f2b(Wl[i] + ((c == o) ? 1.f : 0.f));
  }
  int nb0 = blockIdx.x*64;
  for (int i = tid; i < 4096; i += 256){
    int nn = i >> 6, c = i & 63; int n = nb0 + nn;
    u16 xb = 0, gb = 0;
    if (n < N){
      size_t idx = (size_t)n*64 + c;
      xb = xlin[idx];
      float g = dinv[idx]*(b2f(V[idx]) + U[idx]) + bconv[c];
      gb = f2b(g);
      if (!last) U[idx] = 0.f;
    }
    an[nn*STK + c] = xb;
    an[nn*STK + 64 + c] = gb;
  }
  __syncthreads();
  int w = tid >> 6, lane = tid & 63;
  int m16 = lane & 15, quad = lane >> 4;
  int wbase = w*16;
  v8bf af[4];
  #pragma unroll
  for (int ks = 0; ks < 4; ks++) af[ks] = *(const v8bf*)&an[(wbase+m16)*STK + ks*32 + quad*8];
  v4f acc[4];
  #pragma unroll
  for (int ni = 0; ni < 4; ni++) acc[ni] = (v4f){0.f,0.f,0.f,0.f};
  #pragma unroll
  for (int ks = 0; ks < 4; ks++){
    #pragma unroll
    for (int ni = 0; ni < 4; ni++){
      v8bf bf = *(const v8bf*)&wb[(ni*16+m16)*STK + ks*32 + quad*8];
      acc[ni] = __builtin_amdgcn_mfma_f32_16x16x32_bf16(af[ks], bf, acc[ni], 0, 0, 0);
    }
  }
  if (!last){
    #pragma unroll
    for (int ni = 0; ni < 4; ni++){
      int c = ni*16 + m16;
      float wc = wconv_next[c];
      #pragma unroll
      for (int r = 0; r < 4; r++){
        int n = nb0 + wbase + quad*4 + r;
        if (n < N){
          size_t idx = (size_t)n*64 + c;
          V[idx] = f2b(fmaxf(acc[ni][r], 0.f) * wc * dinv[idx]);
        }
      }
    }
  } else {
    float part[4];
    #pragma unroll
    for (int r = 0; r < 4; r++){
      float p = 0.f;
      int rowl = wbase + quad*4 + r;
      #pragma unroll
      for (int ni = 0; ni < 4; ni++){
        int c = ni*16 + m16;
        float xl = b2f(an[rowl*STK + c]);
        float hr = fmaxf(acc[ni][r], 0.f);
        p += xl*Wo[c] + hr*Wo[64 + c];
      }
      part[r] = p;
    }
    #pragma unroll
    for (int off = 1; off < 16; off <<= 1)
      #pragma unroll
      for (int r = 0; r < 4; r++) part[r] += __shfl_xor(part[r], off, 64);
    if (m16 == 0){
      #pragma unroll
      for (int r = 0; r < 4; r++){
        int n = nb0 + wbase + quad*4 + r;
        if (n < N) out[n] = part[r];
      }
    }
  }
}

extern "C" void kernel_launch(void* const* d_in, const int* in_sizes, int n_in,
                              void* d_out, int out_size, void* d_ws, size_t ws_size,
                              hipStream_t stream){
  const float* x     = (const float*)d_in[0];
  const int*   ei    = (const int*)  d_in[1];
  const float* ea    = (const float*)d_in[2];
  const float* W1    = (const float*)d_in[3];
  const float* W2    = (const float*)d_in[4];
  const float* Wi    = (const float*)d_in[5];
  const float* bi    = (const float*)d_in[6];
  const float* wconv = (const float*)d_in[7];
  const float* bconv = (const float*)d_in[8];
  const float* Wl    = (const float*)d_in[9];
  const float* Wo    = (const float*)d_in[10];
  float* out = (float*)d_out;

  int N = in_sizes[0] / 128;
  int E = in_sizes[2] / 8;
  const int* row = ei;
  const int* col = ei + E;
  int nbk = (N + 31) / 32;

  char* p = (char*)d_ws;
  auto alloc = [&](size_t nbytes){ char* r = p; p += (nbytes + 255) & ~(size_t)255; return r; };

  int*   counts  = (int*)  alloc((size_t)N*4);
  int*   start   = (int*)  alloc((size_t)(N+1)*4);
  int*   bcur    = (int*)  alloc((size_t)nbk*4);
  int*   bsum    = (int*)  alloc(4096);
  u16*   wimg1   = (u16*)  alloc(2048*2);
  u16*   wimg2   = (u16*)  alloc((size_t)64*ST*2);
  u32*   rec     = (u32*)  alloc((size_t)E*24);
  float* U       = (float*)alloc((size_t)N*256);
  float* dinv    = (float*)alloc((size_t)N*256);
  u16*   xlin    = (u16*)  alloc((size_t)N*128);
  u16*   V       = (u16*)  alloc((size_t)N*128);
  int*   ovf_cnt = (int*)  alloc(256);
  u32*   ovf     = (u32*)  alloc((size_t)OVFCAP*24);

  int gE   = (E + 255) / 256;
  int gA   = (E + EPB - 1) / EPB;
  int nb1  = (N + 1023) / 1024;
  int gN64 = (N + 63) / 64;
  int gNH  = (N*64 + 255) / 256;

  hipMemsetAsync(counts, 0, (size_t)N*4, stream);
  hipMemsetAsync(U, 0, (size_t)N*256, stream);
  hipMemsetAsync(ovf_cnt, 0, 4, stream);

  prep_k <<<1, 256, 0, stream>>>(W1, W2, wimg1, wimg2);
  hist_k <<<gE, 256, 0, stream>>>(col, counts, E);
  scan1_k<<<nb1, 1024, 0, stream>>>(counts, start, bsum, N);
  scan2_k<<<1, 1024, 0, stream>>>(bsum, nb1, start, N, E);
  scan3_k<<<nb1, 1024, 0, stream>>>(start, bsum, bcur, N);
  scat1_k<<<gE, 256, 0, stream>>>(row, col, ea, bcur, rec, E);
  scat2_k<<<nbk, 256, 0, stream>>>(start, rec, ovf, ovf_cnt, N);

  agg_k<0><<<gA, 256, 0, stream>>>(rec, (const u32*)wimg1, (const u32*)wimg2, V, U, E);   // degree
  degfin_k<<<gNH, 256, 0, stream>>>(U, dinv, N*64);
  xlin_k  <<<gN64, 256, 0, stream>>>(x, Wi, bi, wconv, dinv, xlin, V, N);

  agg_k<1><<<gA, 256, 0, stream>>>(rec, (const u32*)wimg1, (const u32*)wimg2, V, U, E);
  epi_k   <<<gN64, 256, 0, stream>>>(xlin, dinv, U, V, Wl + 0*8192, bconv +   0, wconv +  64, Wo, out, N, 0);
  agg_k<1><<<gA, 256, 0, stream>>>(rec, (const u32*)wimg1, (const u32*)wimg2, V, U, E);
  epi_k   <<<gN64, 256, 0, stream>>>(xlin, dinv, U, V, Wl + 1*8192, bconv +  64, wconv + 128, Wo, out, N, 0);
  agg_k<1><<<gA, 256, 0, stream>>>(rec, (const u32*)wimg1, (const u32*)wimg2, V, U, E);
  epi_k   <<<gN64, 256, 0, stream>>>(xlin, dinv, U, V, Wl + 2*8192, bconv + 128, wconv      , Wo, out, N, 1);
}